// Round 1
// baseline (286.144 us; speedup 1.0000x reference)
//
#include <hip/hip_runtime.h>

typedef __attribute__((ext_vector_type(4))) float  floatx4;
typedef __attribute__((ext_vector_type(8))) short  short8;
typedef __attribute__((ext_vector_type(4))) short  short4v;
typedef __attribute__((ext_vector_type(8))) __bf16 bf16x8;

#define E_DIM 768
#define T_DIM 2048
#define N_B   2
#define N_H   12
#define H_D   64
#define M_TOT 4096  /* N_B * T_DIM */

__device__ __forceinline__ unsigned short f32_to_bf16(float f) {
  unsigned int u = __float_as_uint(f);
  u += 0x7fffu + ((u >> 16) & 1u);
  return (unsigned short)(u >> 16);
}

// ---- weight convert+transpose: Wt[n][k] = bf16(W[k][n]) ----
__global__ __launch_bounds__(256) void transpose_w(const float* __restrict__ W,
                                                   unsigned short* __restrict__ Wt) {
  __shared__ float tile[32][33];
  int k0 = blockIdx.x * 32, n0 = blockIdx.y * 32;
  int tx = threadIdx.x & 31, ty = threadIdx.x >> 5;  // 32 x 8
  for (int i = 0; i < 4; i++)
    tile[ty + i * 8][tx] = W[(size_t)(k0 + ty + i * 8) * E_DIM + n0 + tx];
  __syncthreads();
  for (int i = 0; i < 4; i++)
    Wt[(size_t)(n0 + ty + i * 8) * E_DIM + k0 + tx] = f32_to_bf16(tile[tx][ty + i * 8]);
}

// ---- QKV projection: out[z][b][h][t][d] = bf16((X W + b) * scale), z in {q,k,v} ----
__global__ __launch_bounds__(256) void gemm_qkv(
    const float* __restrict__ Aq, const float* __restrict__ Ak, const float* __restrict__ Av,
    const unsigned short* __restrict__ WtAll,
    const float* __restrict__ bq, const float* __restrict__ bk, const float* __restrict__ bv,
    unsigned short* __restrict__ outQKV) {
  __shared__ unsigned short As[128 * 40];  // [m][k], pad 40 breaks bank conflicts
  __shared__ unsigned short Bs[128 * 40];  // [n][k]

  const int z = blockIdx.z;
  const float* A    = (z == 0) ? Aq : (z == 1) ? Ak : Av;
  const float* bias = (z == 0) ? bq : (z == 1) ? bk : bv;
  const unsigned short* W = WtAll + (size_t)z * E_DIM * E_DIM;
  unsigned short* out = outQKV + (size_t)z * M_TOT * E_DIM;
  const float scale = (z == 0) ? 0.125f : 1.0f;  // fold 1/sqrt(64) into Q

  const int tid = threadIdx.x;
  const int lane = tid & 63, wv = tid >> 6;
  const int m15 = lane & 15, quad = lane >> 4;
  const int wm = (wv & 1) * 64, wn = (wv >> 1) * 64;
  const int m0 = blockIdx.x * 128, n0 = blockIdx.y * 128;

  floatx4 acc[4][4] = {};

  const int ra = tid >> 3, ca = (tid & 7) * 4;  // A staging: fp32 -> bf16
  const int rb = tid >> 2, cb = (tid & 3) * 8;  // B staging: bf16 copy

  for (int k0 = 0; k0 < E_DIM; k0 += 32) {
    for (int p = 0; p < 4; p++) {
      int row = p * 32 + ra;
      float4 v = *reinterpret_cast<const float4*>(&A[(size_t)(m0 + row) * E_DIM + k0 + ca]);
      short4v w;
      w[0] = (short)f32_to_bf16(v.x);
      w[1] = (short)f32_to_bf16(v.y);
      w[2] = (short)f32_to_bf16(v.z);
      w[3] = (short)f32_to_bf16(v.w);
      *reinterpret_cast<short4v*>(&As[row * 40 + ca]) = w;
    }
    for (int p = 0; p < 2; p++) {
      int row = p * 64 + rb;
      *reinterpret_cast<short8*>(&Bs[row * 40 + cb]) =
          *reinterpret_cast<const short8*>(&W[(size_t)(n0 + row) * E_DIM + k0 + cb]);
    }
    __syncthreads();
    bf16x8 af[4], bfr[4];
    for (int i = 0; i < 4; i++)
      af[i] = *reinterpret_cast<const bf16x8*>(&As[(wm + i * 16 + m15) * 40 + quad * 8]);
    for (int j = 0; j < 4; j++)
      bfr[j] = *reinterpret_cast<const bf16x8*>(&Bs[(wn + j * 16 + m15) * 40 + quad * 8]);
    for (int i = 0; i < 4; i++)
      for (int j = 0; j < 4; j++)
        acc[i][j] = __builtin_amdgcn_mfma_f32_16x16x32_bf16(af[i], bfr[j], acc[i][j], 0, 0, 0);
    __syncthreads();
  }

  for (int i = 0; i < 4; i++)
    for (int j = 0; j < 4; j++) {
      int gn = n0 + wn + j * 16 + m15;
      int h = gn >> 6, d = gn & 63;
      float bso = bias[gn];
      for (int r = 0; r < 4; r++) {
        int gm = m0 + wm + i * 16 + quad * 4 + r;
        int bb = gm >> 11, tt = gm & 2047;
        float v = (acc[i][j][r] + bso) * scale;
        out[(((size_t)bb * N_H + h) * T_DIM + tt) * H_D + d] = f32_to_bf16(v);
      }
    }
}

// ---- flash attention: per block one (b,h) and 64 q rows ----
__global__ __launch_bounds__(256) void attn(const unsigned short* __restrict__ QKV,
                                            unsigned short* __restrict__ ctx) {
  __shared__ unsigned short Qs[64 * 72];
  __shared__ unsigned short Ks[64 * 72];
  __shared__ unsigned short Vs[64 * 68];      // stride 68: 2-way conflicts on u16 reads (free)
  __shared__ unsigned short Ps[4 * 16 * 72];  // per-wave P strip

  const int qt = blockIdx.x, h = blockIdx.y, bb = blockIdx.z;
  const size_t headoff = (((size_t)bb * N_H + h) * T_DIM) * H_D;
  const unsigned short* Qg = QKV + headoff;
  const unsigned short* Kg = QKV + (size_t)M_TOT * E_DIM + headoff;
  const unsigned short* Vg = QKV + 2 * (size_t)M_TOT * E_DIM + headoff;

  const int tid = threadIdx.x, lane = tid & 63, wv = tid >> 6;
  const int m15 = lane & 15, quad = lane >> 4;
  const int q0 = qt * 64;
  const int rs = tid >> 3, cs = (tid & 7) * 8;  // staging: 32 rows x 64 cols per pass

  for (int p = 0; p < 2; p++) {
    int row = p * 32 + rs;
    *reinterpret_cast<short8*>(&Qs[row * 72 + cs]) =
        *reinterpret_cast<const short8*>(&Qg[(size_t)(q0 + row) * H_D + cs]);
  }

  floatx4 o[4] = {};
  float m_i[4], l_i[4];
  for (int r = 0; r < 4; r++) { m_i[r] = -1e30f; l_i[r] = 0.0f; }

  unsigned short* Pw = &Ps[wv * 16 * 72];

  for (int kt = 0; kt < 32; kt++) {
    __syncthreads();  // prior-iteration reads of Ks/Vs/Ps done
    for (int p = 0; p < 2; p++) {
      int row = p * 32 + rs;
      *reinterpret_cast<short8*>(&Ks[row * 72 + cs]) =
          *reinterpret_cast<const short8*>(&Kg[(size_t)(kt * 64 + row) * H_D + cs]);
      short8 v = *reinterpret_cast<const short8*>(&Vg[(size_t)(kt * 64 + row) * H_D + cs]);
      short4v lo = {v[0], v[1], v[2], v[3]}, hi = {v[4], v[5], v[6], v[7]};
      *reinterpret_cast<short4v*>(&Vs[row * 68 + cs]) = lo;
      *reinterpret_cast<short4v*>(&Vs[row * 68 + cs + 4]) = hi;
    }
    __syncthreads();

    // S = Q K^T (Q pre-scaled by 1/8)
    floatx4 s[4] = {};
    for (int kk = 0; kk < 2; kk++) {
      bf16x8 a = *reinterpret_cast<const bf16x8*>(&Qs[(wv * 16 + m15) * 72 + kk * 32 + quad * 8]);
      for (int j = 0; j < 4; j++) {
        bf16x8 b = *reinterpret_cast<const bf16x8*>(&Ks[(j * 16 + m15) * 72 + kk * 32 + quad * 8]);
        s[j] = __builtin_amdgcn_mfma_f32_16x16x32_bf16(a, b, s[j], 0, 0, 0);
      }
    }

    // online softmax; row q = quad*4 + r, cols = j*16 + m15
    float p_[4][4];
    for (int r = 0; r < 4; r++) {
      float mx = fmaxf(fmaxf(s[0][r], s[1][r]), fmaxf(s[2][r], s[3][r]));
      for (int msk = 1; msk < 16; msk <<= 1) mx = fmaxf(mx, __shfl_xor(mx, msk, 64));
      float mnew = fmaxf(m_i[r], mx);
      float sum = 0.0f;
      for (int j = 0; j < 4; j++) {
        float pv = exp2f((s[j][r] - mnew) * 1.44269504089f);
        p_[j][r] = pv;
        sum += pv;
      }
      for (int msk = 1; msk < 16; msk <<= 1) sum += __shfl_xor(sum, msk, 64);
      float alpha = exp2f((m_i[r] - mnew) * 1.44269504089f);
      l_i[r] = l_i[r] * alpha + sum;
      m_i[r] = mnew;
      for (int j = 0; j < 4; j++) o[j][r] = o[j][r] * alpha;
    }

    // P: C-layout regs -> LDS -> A-layout frags
    for (int j = 0; j < 4; j++)
      for (int r = 0; r < 4; r++)
        Pw[(quad * 4 + r) * 72 + j * 16 + m15] = f32_to_bf16(p_[j][r]);
    __syncthreads();

    // O += P V
    for (int kk = 0; kk < 2; kk++) {
      bf16x8 a = *reinterpret_cast<const bf16x8*>(&Pw[m15 * 72 + kk * 32 + quad * 8]);
      for (int j = 0; j < 4; j++) {
        short8 bv_;
        for (int jj = 0; jj < 8; jj++)
          bv_[jj] = (short)Vs[(kk * 32 + quad * 8 + jj) * 68 + j * 16 + m15];
        bf16x8 b = __builtin_bit_cast(bf16x8, bv_);
        o[j] = __builtin_amdgcn_mfma_f32_16x16x32_bf16(a, b, o[j], 0, 0, 0);
      }
    }
  }

  // epilogue: ctx[b*T+q][h*64+d] = o/l
  for (int j = 0; j < 4; j++)
    for (int r = 0; r < 4; r++) {
      int q = q0 + wv * 16 + quad * 4 + r;
      float v = o[j][r] / l_i[r];
      ctx[(size_t)(bb * T_DIM + q) * E_DIM + h * 64 + j * 16 + m15] = f32_to_bf16(v);
    }
}

// ---- output projection: out = ctx @ Wo + bo (fp32 out) ----
__global__ __launch_bounds__(256) void gemm_out(const unsigned short* __restrict__ Actx,
                                                const unsigned short* __restrict__ Wt,
                                                const float* __restrict__ bias,
                                                float* __restrict__ out) {
  __shared__ unsigned short As[128 * 40];
  __shared__ unsigned short Bs[128 * 40];

  const int tid = threadIdx.x;
  const int lane = tid & 63, wv = tid >> 6;
  const int m15 = lane & 15, quad = lane >> 4;
  const int wm = (wv & 1) * 64, wn = (wv >> 1) * 64;
  const int m0 = blockIdx.x * 128, n0 = blockIdx.y * 128;

  floatx4 acc[4][4] = {};
  const int rb = tid >> 2, cb = (tid & 3) * 8;

  for (int k0 = 0; k0 < E_DIM; k0 += 32) {
    for (int p = 0; p < 2; p++) {
      int row = p * 64 + rb;
      *reinterpret_cast<short8*>(&As[row * 40 + cb]) =
          *reinterpret_cast<const short8*>(&Actx[(size_t)(m0 + row) * E_DIM + k0 + cb]);
      *reinterpret_cast<short8*>(&Bs[row * 40 + cb]) =
          *reinterpret_cast<const short8*>(&Wt[(size_t)(n0 + row) * E_DIM + k0 + cb]);
    }
    __syncthreads();
    bf16x8 af[4], bfr[4];
    for (int i = 0; i < 4; i++)
      af[i] = *reinterpret_cast<const bf16x8*>(&As[(wm + i * 16 + m15) * 40 + quad * 8]);
    for (int j = 0; j < 4; j++)
      bfr[j] = *reinterpret_cast<const bf16x8*>(&Bs[(wn + j * 16 + m15) * 40 + quad * 8]);
    for (int i = 0; i < 4; i++)
      for (int j = 0; j < 4; j++)
        acc[i][j] = __builtin_amdgcn_mfma_f32_16x16x32_bf16(af[i], bfr[j], acc[i][j], 0, 0, 0);
    __syncthreads();
  }

  for (int i = 0; i < 4; i++)
    for (int j = 0; j < 4; j++) {
      int gn = n0 + wn + j * 16 + m15;
      float bso = bias[gn];
      for (int r = 0; r < 4; r++) {
        int gm = m0 + wm + i * 16 + quad * 4 + r;
        out[(size_t)gm * E_DIM + gn] = acc[i][j][r] + bso;
      }
    }
}

extern "C" void kernel_launch(void* const* d_in, const int* in_sizes, int n_in,
                              void* d_out, int out_size, void* d_ws, size_t ws_size,
                              hipStream_t stream) {
  const float* query  = (const float*)d_in[0];
  const float* key_in = (const float*)d_in[1];
  const float* value  = (const float*)d_in[2];
  const float* Wq = (const float*)d_in[3];
  const float* bq = (const float*)d_in[4];
  const float* Wk = (const float*)d_in[5];
  const float* bk = (const float*)d_in[6];
  const float* Wv = (const float*)d_in[7];
  const float* bv = (const float*)d_in[8];
  const float* Wo = (const float*)d_in[9];
  const float* bo = (const float*)d_in[10];
  float* out = (float*)d_out;

  // workspace layout (bf16 elements): Wt[4][768][768] | QKV[3][B,H,T,64] | ctx[4096][768]
  unsigned short* ws  = (unsigned short*)d_ws;
  unsigned short* Wt  = ws;
  unsigned short* QKV = ws + (size_t)4 * E_DIM * E_DIM;
  unsigned short* ctx = QKV + (size_t)3 * M_TOT * E_DIM;

  dim3 tb(256);
  transpose_w<<<dim3(24, 24), tb, 0, stream>>>(Wq, Wt + (size_t)0 * E_DIM * E_DIM);
  transpose_w<<<dim3(24, 24), tb, 0, stream>>>(Wk, Wt + (size_t)1 * E_DIM * E_DIM);
  transpose_w<<<dim3(24, 24), tb, 0, stream>>>(Wv, Wt + (size_t)2 * E_DIM * E_DIM);
  transpose_w<<<dim3(24, 24), tb, 0, stream>>>(Wo, Wt + (size_t)3 * E_DIM * E_DIM);

  gemm_qkv<<<dim3(32, 6, 3), tb, 0, stream>>>(query, key_in, value, Wt, bq, bk, bv, QKV);
  attn<<<dim3(32, 12, 2), tb, 0, stream>>>(QKV, ctx);
  gemm_out<<<dim3(32, 6, 1), tb, 0, stream>>>(ctx, Wt + (size_t)3 * E_DIM * E_DIM, bo, out);
  (void)in_sizes; (void)n_in; (void)out_size; (void)ws_size;
}

// Round 2
// 264.500 us; speedup vs baseline: 1.0818x; 1.0818x over previous
//
#include <hip/hip_runtime.h>

typedef __attribute__((ext_vector_type(4))) float  floatx4;
typedef __attribute__((ext_vector_type(8))) short  short8;
typedef __attribute__((ext_vector_type(4))) short  short4v;
typedef __attribute__((ext_vector_type(8))) __bf16 bf16x8;

#define E_DIM 768
#define T_DIM 2048
#define N_B   2
#define N_H   12
#define H_D   64
#define M_TOT 4096  /* N_B * T_DIM */

__device__ __forceinline__ unsigned short f32_to_bf16(float f) {
  unsigned int u = __float_as_uint(f);
  u += 0x7fffu + ((u >> 16) & 1u);
  return (unsigned short)(u >> 16);
}

// barrier that waits LDS only (no vmcnt drain -> global prefetch stays in flight)
__device__ __forceinline__ void lds_barrier() {
  asm volatile("s_waitcnt lgkmcnt(0)\n\ts_barrier" ::: "memory");
}

// ---- weight convert+transpose: Wt[n][k] = bf16(W[k][n]) ----
__global__ __launch_bounds__(256) void transpose_w(const float* __restrict__ W,
                                                   unsigned short* __restrict__ Wt) {
  __shared__ float tile[32][33];
  int k0 = blockIdx.x * 32, n0 = blockIdx.y * 32;
  int tx = threadIdx.x & 31, ty = threadIdx.x >> 5;  // 32 x 8
  for (int i = 0; i < 4; i++)
    tile[ty + i * 8][tx] = W[(size_t)(k0 + ty + i * 8) * E_DIM + n0 + tx];
  __syncthreads();
  for (int i = 0; i < 4; i++)
    Wt[(size_t)(n0 + ty + i * 8) * E_DIM + k0 + tx] = f32_to_bf16(tile[tx][ty + i * 8]);
}

// ---- QKV projection: out[z][b][h][t][d] = bf16((X W + b) * scale), z in {q,k,v} ----
__global__ __launch_bounds__(256) void gemm_qkv(
    const float* __restrict__ Aq, const float* __restrict__ Ak, const float* __restrict__ Av,
    const unsigned short* __restrict__ WtAll,
    const float* __restrict__ bq, const float* __restrict__ bk, const float* __restrict__ bv,
    unsigned short* __restrict__ outQKV) {
  __shared__ unsigned short As[128 * 40];
  __shared__ unsigned short Bs[128 * 40];

  const int z = blockIdx.z;
  const float* A    = (z == 0) ? Aq : (z == 1) ? Ak : Av;
  const float* bias = (z == 0) ? bq : (z == 1) ? bk : bv;
  const unsigned short* W = WtAll + (size_t)z * E_DIM * E_DIM;
  unsigned short* out = outQKV + (size_t)z * M_TOT * E_DIM;
  const float scale = (z == 0) ? 0.125f : 1.0f;

  const int tid = threadIdx.x;
  const int lane = tid & 63, wv = tid >> 6;
  const int m15 = lane & 15, quad = lane >> 4;
  const int wm = (wv & 1) * 64, wn = (wv >> 1) * 64;
  const int m0 = blockIdx.x * 128, n0 = blockIdx.y * 128;

  floatx4 acc[4][4] = {};

  const int ra = tid >> 3, ca = (tid & 7) * 4;
  const int rb = tid >> 2, cb = (tid & 3) * 8;

  for (int k0 = 0; k0 < E_DIM; k0 += 32) {
    for (int p = 0; p < 4; p++) {
      int row = p * 32 + ra;
      float4 v = *reinterpret_cast<const float4*>(&A[(size_t)(m0 + row) * E_DIM + k0 + ca]);
      short4v w;
      w[0] = (short)f32_to_bf16(v.x);
      w[1] = (short)f32_to_bf16(v.y);
      w[2] = (short)f32_to_bf16(v.z);
      w[3] = (short)f32_to_bf16(v.w);
      *reinterpret_cast<short4v*>(&As[row * 40 + ca]) = w;
    }
    for (int p = 0; p < 2; p++) {
      int row = p * 64 + rb;
      *reinterpret_cast<short8*>(&Bs[row * 40 + cb]) =
          *reinterpret_cast<const short8*>(&W[(size_t)(n0 + row) * E_DIM + k0 + cb]);
    }
    __syncthreads();
    bf16x8 af[4], bfr[4];
    for (int i = 0; i < 4; i++)
      af[i] = *reinterpret_cast<const bf16x8*>(&As[(wm + i * 16 + m15) * 40 + quad * 8]);
    for (int j = 0; j < 4; j++)
      bfr[j] = *reinterpret_cast<const bf16x8*>(&Bs[(wn + j * 16 + m15) * 40 + quad * 8]);
    for (int i = 0; i < 4; i++)
      for (int j = 0; j < 4; j++)
        acc[i][j] = __builtin_amdgcn_mfma_f32_16x16x32_bf16(af[i], bfr[j], acc[i][j], 0, 0, 0);
    __syncthreads();
  }

  for (int i = 0; i < 4; i++)
    for (int j = 0; j < 4; j++) {
      int gn = n0 + wn + j * 16 + m15;
      int h = gn >> 6, d = gn & 63;
      float bso = bias[gn];
      for (int r = 0; r < 4; r++) {
        int gm = m0 + wm + i * 16 + quad * 4 + r;
        int bb = gm >> 11, tt = gm & 2047;
        float v = (acc[i][j][r] + bso) * scale;
        out[(((size_t)bb * N_H + h) * T_DIM + tt) * H_D + d] = f32_to_bf16(v);
      }
    }
}

// ---- flash attention: per block one (b,h) and 64 q rows ----
__global__ __launch_bounds__(256) void attn(const unsigned short* __restrict__ QKV,
                                            unsigned short* __restrict__ ctx) {
  __shared__ unsigned short QPs[64 * 72];  // Q staging, then per-wave P strips (wave w owns rows [16w,16w+16))
  __shared__ unsigned short Ks[64 * 72];   // [key][d]
  __shared__ unsigned short Vt[64 * 72];   // transposed: [d][key]

  const int qt = blockIdx.x, h = blockIdx.y, bb = blockIdx.z;
  const size_t headoff = (((size_t)bb * N_H + h) * T_DIM) * H_D;
  const unsigned short* Qg = QKV + headoff;
  const unsigned short* Kg = QKV + (size_t)M_TOT * E_DIM + headoff;
  const unsigned short* Vg = QKV + 2 * (size_t)M_TOT * E_DIM + headoff;

  const int tid = threadIdx.x, lane = tid & 63, wv = tid >> 6;
  const int m15 = lane & 15, quad = lane >> 4;
  const int q0 = qt * 64;
  const int rs = tid >> 3, cs = (tid & 7) * 8;        // K/Q staging map (coalesced)
  const int vkey = tid & 63, vd0 = (tid >> 6) * 8;    // V staging map (key=lane: transpose writes are 2-way/free)

  // prefetch kt=0 K/V into regs (overlaps Q staging)
  short8 kreg[2], vreg[2];
  for (int p = 0; p < 2; p++) {
    kreg[p] = *reinterpret_cast<const short8*>(&Kg[(size_t)(p * 32 + rs) * H_D + cs]);
    vreg[p] = *reinterpret_cast<const short8*>(&Vg[(size_t)vkey * H_D + vd0 + p * 32]);
  }

  // Q staging
  for (int p = 0; p < 2; p++) {
    int row = p * 32 + rs;
    *reinterpret_cast<short8*>(&QPs[row * 72 + cs]) =
        *reinterpret_cast<const short8*>(&Qg[(size_t)(q0 + row) * H_D + cs]);
  }
  lds_barrier();

  // hoist Q fragments (loop-invariant); after this QPs rows are wave-private P strips
  bf16x8 aq[2];
  aq[0] = *reinterpret_cast<const bf16x8*>(&QPs[(wv * 16 + m15) * 72 + 0 * 32 + quad * 8]);
  aq[1] = *reinterpret_cast<const bf16x8*>(&QPs[(wv * 16 + m15) * 72 + 1 * 32 + quad * 8]);

  floatx4 o[4] = {};
  float m_i[4], l_i[4];
  for (int r = 0; r < 4; r++) { m_i[r] = -1e30f; l_i[r] = 0.0f; }

  unsigned short* Pw = &QPs[wv * 16 * 72];

  for (int kt = 0; kt < 32; kt++) {
    lds_barrier();  // all waves done reading Ks/Vt from previous iter
    for (int p = 0; p < 2; p++) {
      *reinterpret_cast<short8*>(&Ks[(p * 32 + rs) * 72 + cs]) = kreg[p];
#pragma unroll
      for (int j = 0; j < 8; j++)
        Vt[(vd0 + p * 32 + j) * 72 + vkey] = (unsigned short)vreg[p][j];
    }
    if (kt + 1 < 32) {  // prefetch next tile; stays in flight across compute (no vmcnt drain at lds_barrier)
      for (int p = 0; p < 2; p++) {
        kreg[p] = *reinterpret_cast<const short8*>(&Kg[(size_t)((kt + 1) * 64 + p * 32 + rs) * H_D + cs]);
        vreg[p] = *reinterpret_cast<const short8*>(&Vg[(size_t)((kt + 1) * 64 + vkey) * H_D + vd0 + p * 32]);
      }
    }
    lds_barrier();  // staging visible

    // S = Q K^T (Q pre-scaled by 1/8)
    floatx4 s[4] = {};
    for (int kk = 0; kk < 2; kk++)
      for (int j = 0; j < 4; j++) {
        bf16x8 b = *reinterpret_cast<const bf16x8*>(&Ks[(j * 16 + m15) * 72 + kk * 32 + quad * 8]);
        s[j] = __builtin_amdgcn_mfma_f32_16x16x32_bf16(aq[kk], b, s[j], 0, 0, 0);
      }

    // online softmax; row q = quad*4 + r, cols = j*16 + m15
    float p_[4][4];
    for (int r = 0; r < 4; r++) {
      float mx = fmaxf(fmaxf(s[0][r], s[1][r]), fmaxf(s[2][r], s[3][r]));
      for (int msk = 1; msk < 16; msk <<= 1) mx = fmaxf(mx, __shfl_xor(mx, msk, 64));
      float mnew = fmaxf(m_i[r], mx);
      float sum = 0.0f;
      for (int j = 0; j < 4; j++) {
        float pv = exp2f((s[j][r] - mnew) * 1.44269504089f);
        p_[j][r] = pv;
        sum += pv;
      }
      for (int msk = 1; msk < 16; msk <<= 1) sum += __shfl_xor(sum, msk, 64);
      float alpha = exp2f((m_i[r] - mnew) * 1.44269504089f);
      l_i[r] = l_i[r] * alpha + sum;
      m_i[r] = mnew;
      for (int j = 0; j < 4; j++) o[j][r] = o[j][r] * alpha;
    }

    // P: C-layout regs -> wave-private LDS strip -> A-layout frags (no block barrier needed)
    for (int j = 0; j < 4; j++)
      for (int r = 0; r < 4; r++)
        Pw[(quad * 4 + r) * 72 + j * 16 + m15] = f32_to_bf16(p_[j][r]);
    asm volatile("s_waitcnt lgkmcnt(0)" ::: "memory");  // wave-local visibility

    // O += P V  (V fragments are contiguous b128 reads from Vt)
    for (int kk = 0; kk < 2; kk++) {
      bf16x8 a = *reinterpret_cast<const bf16x8*>(&Pw[m15 * 72 + kk * 32 + quad * 8]);
      for (int j = 0; j < 4; j++) {
        bf16x8 b = *reinterpret_cast<const bf16x8*>(&Vt[(j * 16 + m15) * 72 + kk * 32 + quad * 8]);
        o[j] = __builtin_amdgcn_mfma_f32_16x16x32_bf16(a, b, o[j], 0, 0, 0);
      }
    }
  }

  // epilogue: ctx[b*T+q][h*64+d] = o/l
  for (int j = 0; j < 4; j++)
    for (int r = 0; r < 4; r++) {
      int q = q0 + wv * 16 + quad * 4 + r;
      float v = o[j][r] / l_i[r];
      ctx[(size_t)(bb * T_DIM + q) * E_DIM + h * 64 + j * 16 + m15] = f32_to_bf16(v);
    }
}

// ---- output projection: out = ctx @ Wo + bo (fp32 out) ----
__global__ __launch_bounds__(256) void gemm_out(const unsigned short* __restrict__ Actx,
                                                const unsigned short* __restrict__ Wt,
                                                const float* __restrict__ bias,
                                                float* __restrict__ out) {
  __shared__ unsigned short As[128 * 40];
  __shared__ unsigned short Bs[128 * 40];

  const int tid = threadIdx.x;
  const int lane = tid & 63, wv = tid >> 6;
  const int m15 = lane & 15, quad = lane >> 4;
  const int wm = (wv & 1) * 64, wn = (wv >> 1) * 64;
  const int m0 = blockIdx.x * 128, n0 = blockIdx.y * 128;

  floatx4 acc[4][4] = {};
  const int rb = tid >> 2, cb = (tid & 3) * 8;

  for (int k0 = 0; k0 < E_DIM; k0 += 32) {
    for (int p = 0; p < 2; p++) {
      int row = p * 64 + rb;
      *reinterpret_cast<short8*>(&As[row * 40 + cb]) =
          *reinterpret_cast<const short8*>(&Actx[(size_t)(m0 + row) * E_DIM + k0 + cb]);
      *reinterpret_cast<short8*>(&Bs[row * 40 + cb]) =
          *reinterpret_cast<const short8*>(&Wt[(size_t)(n0 + row) * E_DIM + k0 + cb]);
    }
    __syncthreads();
    bf16x8 af[4], bfr[4];
    for (int i = 0; i < 4; i++)
      af[i] = *reinterpret_cast<const bf16x8*>(&As[(wm + i * 16 + m15) * 40 + quad * 8]);
    for (int j = 0; j < 4; j++)
      bfr[j] = *reinterpret_cast<const bf16x8*>(&Bs[(wn + j * 16 + m15) * 40 + quad * 8]);
    for (int i = 0; i < 4; i++)
      for (int j = 0; j < 4; j++)
        acc[i][j] = __builtin_amdgcn_mfma_f32_16x16x32_bf16(af[i], bfr[j], acc[i][j], 0, 0, 0);
    __syncthreads();
  }

  for (int i = 0; i < 4; i++)
    for (int j = 0; j < 4; j++) {
      int gn = n0 + wn + j * 16 + m15;
      float bso = bias[gn];
      for (int r = 0; r < 4; r++) {
        int gm = m0 + wm + i * 16 + quad * 4 + r;
        out[(size_t)gm * E_DIM + gn] = acc[i][j][r] + bso;
      }
    }
}

extern "C" void kernel_launch(void* const* d_in, const int* in_sizes, int n_in,
                              void* d_out, int out_size, void* d_ws, size_t ws_size,
                              hipStream_t stream) {
  const float* query  = (const float*)d_in[0];
  const float* key_in = (const float*)d_in[1];
  const float* value  = (const float*)d_in[2];
  const float* Wq = (const float*)d_in[3];
  const float* bq = (const float*)d_in[4];
  const float* Wk = (const float*)d_in[5];
  const float* bk = (const float*)d_in[6];
  const float* Wv = (const float*)d_in[7];
  const float* bv = (const float*)d_in[8];
  const float* Wo = (const float*)d_in[9];
  const float* bo = (const float*)d_in[10];
  float* out = (float*)d_out;

  unsigned short* ws  = (unsigned short*)d_ws;
  unsigned short* Wt  = ws;
  unsigned short* QKV = ws + (size_t)4 * E_DIM * E_DIM;
  unsigned short* ctx = QKV + (size_t)3 * M_TOT * E_DIM;

  dim3 tb(256);
  transpose_w<<<dim3(24, 24), tb, 0, stream>>>(Wq, Wt + (size_t)0 * E_DIM * E_DIM);
  transpose_w<<<dim3(24, 24), tb, 0, stream>>>(Wk, Wt + (size_t)1 * E_DIM * E_DIM);
  transpose_w<<<dim3(24, 24), tb, 0, stream>>>(Wv, Wt + (size_t)2 * E_DIM * E_DIM);
  transpose_w<<<dim3(24, 24), tb, 0, stream>>>(Wo, Wt + (size_t)3 * E_DIM * E_DIM);

  gemm_qkv<<<dim3(32, 6, 3), tb, 0, stream>>>(query, key_in, value, Wt, bq, bk, bv, QKV);
  attn<<<dim3(32, 12, 2), tb, 0, stream>>>(QKV, ctx);
  gemm_out<<<dim3(32, 6, 1), tb, 0, stream>>>(ctx, Wt + (size_t)3 * E_DIM * E_DIM, bo, out);
  (void)in_sizes; (void)n_in; (void)out_size; (void)ws_size;
}

// Round 3
// 215.398 us; speedup vs baseline: 1.3284x; 1.2280x over previous
//
#include <hip/hip_runtime.h>
#include <math.h>

typedef __attribute__((ext_vector_type(4))) float  floatx4;
typedef __attribute__((ext_vector_type(8))) short  short8;
typedef __attribute__((ext_vector_type(4))) short  short4v;
typedef __attribute__((ext_vector_type(8))) __bf16 bf16x8;

#define E_DIM 768
#define T_DIM 2048
#define N_B   2
#define N_H   12
#define H_D   64
#define M_TOT 4096  /* N_B * T_DIM */

// 0.125 * log2(e): folded into Q so exp2() applies directly to QK^T output
#define Q_SCALE 0.1803368801111204f

__device__ __forceinline__ unsigned short f32_to_bf16(float f) {
  unsigned int u = __float_as_uint(f);
  u += 0x7fffu + ((u >> 16) & 1u);
  return (unsigned short)(u >> 16);
}

// barrier that waits LDS only (no vmcnt drain -> global prefetch stays in flight)
__device__ __forceinline__ void lds_barrier() {
  asm volatile("s_waitcnt lgkmcnt(0)\n\ts_barrier" ::: "memory");
}

__device__ __forceinline__ void gload_lds16(const unsigned short* g, unsigned short* l) {
  __builtin_amdgcn_global_load_lds(
      (const __attribute__((address_space(1))) unsigned int*)(const void*)g,
      (__attribute__((address_space(3))) unsigned int*)(void*)l, 16, 0, 0);
}

// ---- input convert: Xb[z][m][k] = bf16(x[m][k]) ----
__global__ __launch_bounds__(256) void convert_x(const float* __restrict__ q,
                                                 const float* __restrict__ k,
                                                 const float* __restrict__ v,
                                                 unsigned short* __restrict__ Xb) {
  const int z = blockIdx.y;
  const float* src = (z == 0) ? q : (z == 1) ? k : v;
  size_t idx = ((size_t)blockIdx.x * 256 + threadIdx.x) * 4;
  float4 val = *reinterpret_cast<const float4*>(&src[idx]);
  short4v o;
  o[0] = (short)f32_to_bf16(val.x);
  o[1] = (short)f32_to_bf16(val.y);
  o[2] = (short)f32_to_bf16(val.z);
  o[3] = (short)f32_to_bf16(val.w);
  *reinterpret_cast<short4v*>(&Xb[(size_t)z * M_TOT * E_DIM + idx]) = o;
}

// ---- weight convert+transpose: Wt[n][k] = bf16(W[k][n]) ----
__global__ __launch_bounds__(256) void transpose_w(const float* __restrict__ W,
                                                   unsigned short* __restrict__ Wt) {
  __shared__ float tile[32][33];
  int k0 = blockIdx.x * 32, n0 = blockIdx.y * 32;
  int tx = threadIdx.x & 31, ty = threadIdx.x >> 5;
  for (int i = 0; i < 4; i++)
    tile[ty + i * 8][tx] = W[(size_t)(k0 + ty + i * 8) * E_DIM + n0 + tx];
  __syncthreads();
  for (int i = 0; i < 4; i++)
    Wt[(size_t)(n0 + ty + i * 8) * E_DIM + k0 + tx] = f32_to_bf16(tile[tx][ty + i * 8]);
}

// ---- QKV projection (m97-style global_load_lds staging) ----
__global__ __launch_bounds__(256) void gemm_qkv(const unsigned short* __restrict__ Xb,
                                                const unsigned short* __restrict__ WtAll,
                                                const float* __restrict__ bq,
                                                const float* __restrict__ bk,
                                                const float* __restrict__ bv,
                                                unsigned short* __restrict__ outQKV) {
  __shared__ unsigned short As[128 * 32];  // unpadded: required by global_load_lds, bank-balanced for b128
  __shared__ unsigned short Bs[128 * 32];

  const int z = blockIdx.z;
  const unsigned short* A = Xb + (size_t)z * M_TOT * E_DIM;
  const float* bias = (z == 0) ? bq : (z == 1) ? bk : bv;
  const unsigned short* W = WtAll + (size_t)z * E_DIM * E_DIM;
  unsigned short* out = outQKV + (size_t)z * M_TOT * E_DIM;
  const float scale = (z == 0) ? Q_SCALE : 1.0f;

  const int tid = threadIdx.x;
  const int lane = tid & 63, wv = tid >> 6;
  const int m15 = lane & 15, quad = lane >> 4;
  const int wm = (wv & 1) * 64, wn = (wv >> 1) * 64;
  const int m0 = blockIdx.x * 128, n0 = blockIdx.y * 128;

  floatx4 acc[4][4] = {};
  const int srow = lane >> 2, scol = (lane & 3) * 8;  // within-chunk element map

  for (int k0 = 0; k0 < E_DIM; k0 += 32) {
    for (int cc = 0; cc < 2; cc++) {
      int c = wv * 2 + cc;
      gload_lds16(&A[(size_t)(m0 + c * 16 + srow) * E_DIM + k0 + scol], &As[c * 512]);
      gload_lds16(&W[(size_t)(n0 + c * 16 + srow) * E_DIM + k0 + scol], &Bs[c * 512]);
    }
    __syncthreads();  // full drain: global_load_lds completion is vmcnt-tracked
    bf16x8 af[4], bfr[4];
    for (int i = 0; i < 4; i++)
      af[i] = *reinterpret_cast<const bf16x8*>(&As[(wm + i * 16 + m15) * 32 + quad * 8]);
    for (int j = 0; j < 4; j++)
      bfr[j] = *reinterpret_cast<const bf16x8*>(&Bs[(wn + j * 16 + m15) * 32 + quad * 8]);
    for (int i = 0; i < 4; i++)
      for (int j = 0; j < 4; j++)
        acc[i][j] = __builtin_amdgcn_mfma_f32_16x16x32_bf16(af[i], bfr[j], acc[i][j], 0, 0, 0);
    __syncthreads();
  }

  for (int i = 0; i < 4; i++)
    for (int j = 0; j < 4; j++) {
      int gn = n0 + wn + j * 16 + m15;
      int h = gn >> 6, d = gn & 63;
      float bso = bias[gn];
      for (int r = 0; r < 4; r++) {
        int gm = m0 + wm + i * 16 + quad * 4 + r;
        int bb = gm >> 11, tt = gm & 2047;
        float v = (acc[i][j][r] + bso) * scale;
        out[(((size_t)bb * N_H + h) * T_DIM + tt) * H_D + d] = f32_to_bf16(v);
      }
    }
}

// ---- V transpose: VT[b][h][d][t] = QKV_v[b][h][t][d] ----
__global__ __launch_bounds__(256) void transpose_v(const unsigned short* __restrict__ Vg_all,
                                                   unsigned short* __restrict__ VT) {
  __shared__ unsigned short tile[64 * 72];  // [d][t], stride 72 keeps b128 reads aligned+balanced
  const int t0 = blockIdx.x * 64, h = blockIdx.y, bb = blockIdx.z;
  const unsigned short* Vg = Vg_all + (((size_t)bb * N_H + h) * T_DIM) * H_D;
  unsigned short* VTh = VT + (((size_t)bb * N_H + h) * H_D) * T_DIM;
  const int tid = threadIdx.x;
  const int tloc = tid & 63, d0 = (tid >> 6) * 16;

  short8 r0 = *reinterpret_cast<const short8*>(&Vg[(size_t)(t0 + tloc) * H_D + d0]);
  short8 r1 = *reinterpret_cast<const short8*>(&Vg[(size_t)(t0 + tloc) * H_D + d0 + 8]);
#pragma unroll
  for (int j = 0; j < 8; j++) {
    tile[(d0 + j) * 72 + tloc] = (unsigned short)r0[j];
    tile[(d0 + 8 + j) * 72 + tloc] = (unsigned short)r1[j];
  }
  __syncthreads();
  const int d = tid >> 2, ts = (tid & 3) * 16;
  short8 w0 = *reinterpret_cast<const short8*>(&tile[d * 72 + ts]);
  short8 w1 = *reinterpret_cast<const short8*>(&tile[d * 72 + ts + 8]);
  *reinterpret_cast<short8*>(&VTh[(size_t)d * T_DIM + t0 + ts]) = w0;
  *reinterpret_cast<short8*>(&VTh[(size_t)d * T_DIM + t0 + ts + 8]) = w1;
}

// ---- flash attention, no-max softmax + ones-MFMA row sums + double-buffered K/V ----
__global__ __launch_bounds__(256) void attn(const unsigned short* __restrict__ QKV,
                                            const unsigned short* __restrict__ VT,
                                            unsigned short* __restrict__ ctx) {
  __shared__ unsigned short QPs[64 * 72];   // Q staging, then per-wave P strips
  __shared__ unsigned short Ks[2][64 * 72]; // [key][d] double-buffered
  __shared__ unsigned short Vs[2][64 * 72]; // [d][key] double-buffered

  const int qt = blockIdx.x, h = blockIdx.y, bb = blockIdx.z;
  const size_t headoff = (((size_t)bb * N_H + h) * T_DIM) * H_D;
  const unsigned short* Qg = QKV + headoff;
  const unsigned short* Kg = QKV + (size_t)M_TOT * E_DIM + headoff;
  const unsigned short* VTg = VT + (((size_t)bb * N_H + h) * H_D) * T_DIM;

  const int tid = threadIdx.x, lane = tid & 63, wv = tid >> 6;
  const int m15 = lane & 15, quad = lane >> 4;
  const int q0 = qt * 64;
  const int rs = tid >> 3, cs = (tid & 7) * 8;  // staging map: 32 rows x 64 cols per pass

  // Q staging
  for (int p = 0; p < 2; p++)
    *reinterpret_cast<short8*>(&QPs[(p * 32 + rs) * 72 + cs]) =
        *reinterpret_cast<const short8*>(&Qg[(size_t)(q0 + p * 32 + rs) * H_D + cs]);

  // prefetch tile 0 into regs
  short8 kreg[2], vreg[2];
  for (int p = 0; p < 2; p++) {
    kreg[p] = *reinterpret_cast<const short8*>(&Kg[(size_t)(p * 32 + rs) * H_D + cs]);
    vreg[p] = *reinterpret_cast<const short8*>(&VTg[(size_t)(p * 32 + rs) * T_DIM + cs]);
  }

  lds_barrier();

  // hoist Q fragments; QPs becomes per-wave P strips after this
  bf16x8 aq[2];
  aq[0] = *reinterpret_cast<const bf16x8*>(&QPs[(wv * 16 + m15) * 72 + 0 + quad * 8]);
  aq[1] = *reinterpret_cast<const bf16x8*>(&QPs[(wv * 16 + m15) * 72 + 32 + quad * 8]);

  // write tile 0 into buf 0, prefetch tile 1
  for (int p = 0; p < 2; p++) {
    *reinterpret_cast<short8*>(&Ks[0][(p * 32 + rs) * 72 + cs]) = kreg[p];
    *reinterpret_cast<short8*>(&Vs[0][(p * 32 + rs) * 72 + cs]) = vreg[p];
  }
  for (int p = 0; p < 2; p++) {
    kreg[p] = *reinterpret_cast<const short8*>(&Kg[(size_t)(64 + p * 32 + rs) * H_D + cs]);
    vreg[p] = *reinterpret_cast<const short8*>(&VTg[(size_t)(p * 32 + rs) * T_DIM + 64 + cs]);
  }

  floatx4 o[4] = {};
  floatx4 lacc = {};
  const short8 ones_s = {0x3f80, 0x3f80, 0x3f80, 0x3f80, 0x3f80, 0x3f80, 0x3f80, 0x3f80};
  const bf16x8 onesb = __builtin_bit_cast(bf16x8, ones_s);
  unsigned short* Pw = &QPs[wv * 16 * 72];
  const int swz_r = ((m15 >> 2) & 3) << 3;  // read-side XOR swizzle (row = m15)

  for (int kt = 0; kt < 32; kt++) {
    const int cur = kt & 1, nxt = cur ^ 1;
    lds_barrier();  // tile kt visible; all waves done reading buf nxt
    if (kt + 1 < 32) {
      for (int p = 0; p < 2; p++) {
        *reinterpret_cast<short8*>(&Ks[nxt][(p * 32 + rs) * 72 + cs]) = kreg[p];
        *reinterpret_cast<short8*>(&Vs[nxt][(p * 32 + rs) * 72 + cs]) = vreg[p];
      }
      if (kt + 2 < 32)
        for (int p = 0; p < 2; p++) {
          kreg[p] = *reinterpret_cast<const short8*>(&Kg[(size_t)((kt + 2) * 64 + p * 32 + rs) * H_D + cs]);
          vreg[p] = *reinterpret_cast<const short8*>(&VTg[(size_t)(p * 32 + rs) * T_DIM + (kt + 2) * 64 + cs]);
        }
    }

    // S = Q' K^T  (Q' carries 0.125*log2e)
    floatx4 s[4] = {};
    for (int kk = 0; kk < 2; kk++)
      for (int j = 0; j < 4; j++) {
        bf16x8 b = *reinterpret_cast<const bf16x8*>(&Ks[cur][(j * 16 + m15) * 72 + kk * 32 + quad * 8]);
        s[j] = __builtin_amdgcn_mfma_f32_16x16x32_bf16(aq[kk], b, s[j], 0, 0, 0);
      }

    // P = exp2(S), written to wave-private strip with XOR swizzle (conflict-free)
    for (int j = 0; j < 4; j++)
      for (int r = 0; r < 4; r++) {
        float pv = exp2f(s[j][r]);
        Pw[(quad * 4 + r) * 72 + ((j * 16 + m15) ^ (quad << 3))] = f32_to_bf16(pv);
      }
    asm volatile("s_waitcnt lgkmcnt(0)" ::: "memory");  // wave-local P visibility

    // O += P V ; l += P * ones (row sums, no shuffles)
    for (int kk = 0; kk < 2; kk++) {
      bf16x8 a = *reinterpret_cast<const bf16x8*>(&Pw[m15 * 72 + ((kk * 32 + quad * 8) ^ swz_r)]);
      lacc = __builtin_amdgcn_mfma_f32_16x16x32_bf16(a, onesb, lacc, 0, 0, 0);
      for (int j = 0; j < 4; j++) {
        bf16x8 b = *reinterpret_cast<const bf16x8*>(&Vs[cur][(j * 16 + m15) * 72 + kk * 32 + quad * 8]);
        o[j] = __builtin_amdgcn_mfma_f32_16x16x32_bf16(a, b, o[j], 0, 0, 0);
      }
    }
  }

  // epilogue: ctx[b*T+q][h*64+d] = o / l
  for (int j = 0; j < 4; j++)
    for (int r = 0; r < 4; r++) {
      int q = q0 + wv * 16 + quad * 4 + r;
      float v = o[j][r] / lacc[r];
      ctx[(size_t)(bb * T_DIM + q) * E_DIM + h * 64 + j * 16 + m15] = f32_to_bf16(v);
    }
}

// ---- output projection: out = ctx @ Wo + bo (fp32), 64x128 tiles for grid=384 ----
__global__ __launch_bounds__(256) void gemm_out(const unsigned short* __restrict__ Actx,
                                                const unsigned short* __restrict__ Wt,
                                                const float* __restrict__ bias,
                                                float* __restrict__ out) {
  __shared__ unsigned short As[64 * 32];
  __shared__ unsigned short Bs[128 * 32];

  const int tid = threadIdx.x;
  const int lane = tid & 63, wv = tid >> 6;
  const int m15 = lane & 15, quad = lane >> 4;
  const int wm = (wv & 1) * 32, wn = (wv >> 1) * 64;
  const int m0 = blockIdx.x * 64, n0 = blockIdx.y * 128;

  floatx4 acc[2][4] = {};
  const int srow = lane >> 2, scol = (lane & 3) * 8;

  for (int k0 = 0; k0 < E_DIM; k0 += 32) {
    gload_lds16(&Actx[(size_t)(m0 + wv * 16 + srow) * E_DIM + k0 + scol], &As[wv * 512]);
    for (int cc = 0; cc < 2; cc++) {
      int c = wv * 2 + cc;
      gload_lds16(&Wt[(size_t)(n0 + c * 16 + srow) * E_DIM + k0 + scol], &Bs[c * 512]);
    }
    __syncthreads();
    bf16x8 af[2], bfr[4];
    for (int i = 0; i < 2; i++)
      af[i] = *reinterpret_cast<const bf16x8*>(&As[(wm + i * 16 + m15) * 32 + quad * 8]);
    for (int j = 0; j < 4; j++)
      bfr[j] = *reinterpret_cast<const bf16x8*>(&Bs[(wn + j * 16 + m15) * 32 + quad * 8]);
    for (int i = 0; i < 2; i++)
      for (int j = 0; j < 4; j++)
        acc[i][j] = __builtin_amdgcn_mfma_f32_16x16x32_bf16(af[i], bfr[j], acc[i][j], 0, 0, 0);
    __syncthreads();
  }

  for (int i = 0; i < 2; i++)
    for (int j = 0; j < 4; j++) {
      int gn = n0 + wn + j * 16 + m15;
      float bso = bias[gn];
      for (int r = 0; r < 4; r++) {
        int gm = m0 + wm + i * 16 + quad * 4 + r;
        out[(size_t)gm * E_DIM + gn] = acc[i][j][r] + bso;
      }
    }
}

extern "C" void kernel_launch(void* const* d_in, const int* in_sizes, int n_in,
                              void* d_out, int out_size, void* d_ws, size_t ws_size,
                              hipStream_t stream) {
  const float* query  = (const float*)d_in[0];
  const float* key_in = (const float*)d_in[1];
  const float* value  = (const float*)d_in[2];
  const float* Wq = (const float*)d_in[3];
  const float* bq = (const float*)d_in[4];
  const float* Wk = (const float*)d_in[5];
  const float* bk = (const float*)d_in[6];
  const float* Wv = (const float*)d_in[7];
  const float* bv = (const float*)d_in[8];
  const float* Wo = (const float*)d_in[9];
  const float* bo = (const float*)d_in[10];
  float* out = (float*)d_out;

  // ws layout (bf16): Wt[4][768][768] | Xb[3][4096][768] | QKV[3][4096][768] | VT[2][12][64][2048] | ctx[4096][768]
  unsigned short* ws  = (unsigned short*)d_ws;
  unsigned short* Wt  = ws;
  unsigned short* Xb  = Wt + (size_t)4 * E_DIM * E_DIM;
  unsigned short* QKV = Xb + (size_t)3 * M_TOT * E_DIM;
  unsigned short* VT  = QKV + (size_t)3 * M_TOT * E_DIM;
  unsigned short* ctx = VT + (size_t)N_B * N_H * H_D * T_DIM;

  dim3 tb(256);
  convert_x<<<dim3(M_TOT * E_DIM / 1024, 3), tb, 0, stream>>>(query, key_in, value, Xb);
  transpose_w<<<dim3(24, 24), tb, 0, stream>>>(Wq, Wt + (size_t)0 * E_DIM * E_DIM);
  transpose_w<<<dim3(24, 24), tb, 0, stream>>>(Wk, Wt + (size_t)1 * E_DIM * E_DIM);
  transpose_w<<<dim3(24, 24), tb, 0, stream>>>(Wv, Wt + (size_t)2 * E_DIM * E_DIM);
  transpose_w<<<dim3(24, 24), tb, 0, stream>>>(Wo, Wt + (size_t)3 * E_DIM * E_DIM);

  gemm_qkv<<<dim3(32, 6, 3), tb, 0, stream>>>(Xb, Wt, bq, bk, bv, QKV);
  transpose_v<<<dim3(32, 12, 2), tb, 0, stream>>>(QKV + (size_t)2 * M_TOT * E_DIM, VT);
  attn<<<dim3(32, 12, 2), tb, 0, stream>>>(QKV, VT, ctx);
  gemm_out<<<dim3(64, 6), tb, 0, stream>>>(ctx, Wt + (size_t)3 * E_DIM * E_DIM, bo, out);
  (void)in_sizes; (void)n_in; (void)out_size; (void)ws_size;
}

// Round 4
// 202.710 us; speedup vs baseline: 1.4116x; 1.0626x over previous
//
#include <hip/hip_runtime.h>
#include <math.h>

typedef __attribute__((ext_vector_type(4))) float  floatx4;
typedef __attribute__((ext_vector_type(8))) short  short8;
typedef __attribute__((ext_vector_type(4))) short  short4v;
typedef __attribute__((ext_vector_type(8))) __bf16 bf16x8;

#define E_DIM 768
#define T_DIM 2048
#define N_B   2
#define N_H   12
#define H_D   64
#define M_TOT 4096  /* N_B * T_DIM */

// 0.125 * log2(e): folded into Q so exp2() applies directly to QK^T output
#define Q_SCALE 0.1803368801111204f

#if __has_builtin(__builtin_amdgcn_exp2f)
#define EXP2F(x) __builtin_amdgcn_exp2f(x)
#else
#define EXP2F(x) exp2f(x)
#endif
#if __has_builtin(__builtin_amdgcn_rcpf)
#define RCPF(x) __builtin_amdgcn_rcpf(x)
#else
#define RCPF(x) (1.0f / (x))
#endif

__device__ __forceinline__ unsigned short f32_to_bf16(float f) {
  unsigned int u = __float_as_uint(f);
  u += 0x7fffu + ((u >> 16) & 1u);
  return (unsigned short)(u >> 16);
}

// truncating f32->bf16 (bias cancels in o/l since num+denom share P)
__device__ __forceinline__ unsigned short f32_to_bf16_trunc(float f) {
  return (unsigned short)(__float_as_uint(f) >> 16);
}

// barrier that waits LDS only (no vmcnt drain -> global prefetch stays in flight)
__device__ __forceinline__ void lds_barrier() {
  asm volatile("s_waitcnt lgkmcnt(0)\n\ts_barrier" ::: "memory");
}

__device__ __forceinline__ void gload_lds16(const unsigned short* g, unsigned short* l) {
  __builtin_amdgcn_global_load_lds(
      (const __attribute__((address_space(1))) unsigned int*)(const void*)g,
      (__attribute__((address_space(3))) unsigned int*)(void*)l, 16, 0, 0);
}

// ---- input convert: Xb[z][m][k] = bf16(x[m][k]) ----
__global__ __launch_bounds__(256) void convert_x(const float* __restrict__ q,
                                                 const float* __restrict__ k,
                                                 const float* __restrict__ v,
                                                 unsigned short* __restrict__ Xb) {
  const int z = blockIdx.y;
  const float* src = (z == 0) ? q : (z == 1) ? k : v;
  size_t idx = ((size_t)blockIdx.x * 256 + threadIdx.x) * 4;
  float4 val = *reinterpret_cast<const float4*>(&src[idx]);
  short4v o;
  o[0] = (short)f32_to_bf16(val.x);
  o[1] = (short)f32_to_bf16(val.y);
  o[2] = (short)f32_to_bf16(val.z);
  o[3] = (short)f32_to_bf16(val.w);
  *reinterpret_cast<short4v*>(&Xb[(size_t)z * M_TOT * E_DIM + idx]) = o;
}

// ---- weight convert+transpose (all 4 weights, one launch): Wt[z][n][k] = bf16(W[z][k][n]) ----
__global__ __launch_bounds__(256) void transpose_w4(const float* __restrict__ W0,
                                                    const float* __restrict__ W1,
                                                    const float* __restrict__ W2,
                                                    const float* __restrict__ W3,
                                                    unsigned short* __restrict__ Wt) {
  __shared__ float tile[32][33];
  const int z = blockIdx.z;
  const float* W = (z == 0) ? W0 : (z == 1) ? W1 : (z == 2) ? W2 : W3;
  unsigned short* dst = Wt + (size_t)z * E_DIM * E_DIM;
  int k0 = blockIdx.x * 32, n0 = blockIdx.y * 32;
  int tx = threadIdx.x & 31, ty = threadIdx.x >> 5;
  for (int i = 0; i < 4; i++)
    tile[ty + i * 8][tx] = W[(size_t)(k0 + ty + i * 8) * E_DIM + n0 + tx];
  __syncthreads();
  for (int i = 0; i < 4; i++)
    dst[(size_t)(n0 + ty + i * 8) * E_DIM + k0 + tx] = f32_to_bf16(tile[tx][ty + i * 8]);
}

// ---- QKV projection (m97-style global_load_lds staging) ----
__global__ __launch_bounds__(256) void gemm_qkv(const unsigned short* __restrict__ Xb,
                                                const unsigned short* __restrict__ WtAll,
                                                const float* __restrict__ bq,
                                                const float* __restrict__ bk,
                                                const float* __restrict__ bv,
                                                unsigned short* __restrict__ outQKV) {
  __shared__ unsigned short As[128 * 32];
  __shared__ unsigned short Bs[128 * 32];

  const int z = blockIdx.z;
  const unsigned short* A = Xb + (size_t)z * M_TOT * E_DIM;
  const float* bias = (z == 0) ? bq : (z == 1) ? bk : bv;
  const unsigned short* W = WtAll + (size_t)z * E_DIM * E_DIM;
  unsigned short* out = outQKV + (size_t)z * M_TOT * E_DIM;
  const float scale = (z == 0) ? Q_SCALE : 1.0f;

  const int tid = threadIdx.x;
  const int lane = tid & 63, wv = tid >> 6;
  const int m15 = lane & 15, quad = lane >> 4;
  const int wm = (wv & 1) * 64, wn = (wv >> 1) * 64;
  const int m0 = blockIdx.x * 128, n0 = blockIdx.y * 128;

  floatx4 acc[4][4] = {};
  const int srow = lane >> 2, scol = (lane & 3) * 8;

  for (int k0 = 0; k0 < E_DIM; k0 += 32) {
    for (int cc = 0; cc < 2; cc++) {
      int c = wv * 2 + cc;
      gload_lds16(&A[(size_t)(m0 + c * 16 + srow) * E_DIM + k0 + scol], &As[c * 512]);
      gload_lds16(&W[(size_t)(n0 + c * 16 + srow) * E_DIM + k0 + scol], &Bs[c * 512]);
    }
    __syncthreads();
    bf16x8 af[4], bfr[4];
    for (int i = 0; i < 4; i++)
      af[i] = *reinterpret_cast<const bf16x8*>(&As[(wm + i * 16 + m15) * 32 + quad * 8]);
    for (int j = 0; j < 4; j++)
      bfr[j] = *reinterpret_cast<const bf16x8*>(&Bs[(wn + j * 16 + m15) * 32 + quad * 8]);
    for (int i = 0; i < 4; i++)
      for (int j = 0; j < 4; j++)
        acc[i][j] = __builtin_amdgcn_mfma_f32_16x16x32_bf16(af[i], bfr[j], acc[i][j], 0, 0, 0);
    __syncthreads();
  }

  for (int i = 0; i < 4; i++)
    for (int j = 0; j < 4; j++) {
      int gn = n0 + wn + j * 16 + m15;
      int h = gn >> 6, d = gn & 63;
      float bso = bias[gn];
      for (int r = 0; r < 4; r++) {
        int gm = m0 + wm + i * 16 + quad * 4 + r;
        int bb = gm >> 11, tt = gm & 2047;
        float v = (acc[i][j][r] + bso) * scale;
        out[(((size_t)bb * N_H + h) * T_DIM + tt) * H_D + d] = f32_to_bf16(v);
      }
    }
}

// ---- V transpose: VT[b][h][d][t] = QKV_v[b][h][t][d] ----
__global__ __launch_bounds__(256) void transpose_v(const unsigned short* __restrict__ Vg_all,
                                                   unsigned short* __restrict__ VT) {
  __shared__ unsigned short tile[64 * 72];
  const int t0 = blockIdx.x * 64, h = blockIdx.y, bb = blockIdx.z;
  const unsigned short* Vg = Vg_all + (((size_t)bb * N_H + h) * T_DIM) * H_D;
  unsigned short* VTh = VT + (((size_t)bb * N_H + h) * H_D) * T_DIM;
  const int tid = threadIdx.x;
  const int tloc = tid & 63, d0 = (tid >> 6) * 16;

  short8 r0 = *reinterpret_cast<const short8*>(&Vg[(size_t)(t0 + tloc) * H_D + d0]);
  short8 r1 = *reinterpret_cast<const short8*>(&Vg[(size_t)(t0 + tloc) * H_D + d0 + 8]);
#pragma unroll
  for (int j = 0; j < 8; j++) {
    tile[(d0 + j) * 72 + tloc] = (unsigned short)r0[j];
    tile[(d0 + 8 + j) * 72 + tloc] = (unsigned short)r1[j];
  }
  __syncthreads();
  const int d = tid >> 2, ts = (tid & 3) * 16;
  short8 w0 = *reinterpret_cast<const short8*>(&tile[d * 72 + ts]);
  short8 w1 = *reinterpret_cast<const short8*>(&tile[d * 72 + ts + 8]);
  *reinterpret_cast<short8*>(&VTh[(size_t)d * T_DIM + t0 + ts]) = w0;
  *reinterpret_cast<short8*>(&VTh[(size_t)d * T_DIM + t0 + ts + 8]) = w1;
}

// ---- flash attention: no-max softmax, lagged PV (P round-trip off critical path) ----
__global__ __launch_bounds__(256) void attn(const unsigned short* __restrict__ QKV,
                                            const unsigned short* __restrict__ VT,
                                            unsigned short* __restrict__ ctx) {
  __shared__ unsigned short Qs[64 * 72];     // Q staging -> P strip set A (wave-private rows)
  __shared__ unsigned short Sb[64 * 72];     // P strip set B
  __shared__ unsigned short Ks[64 * 72];     // K tile [key][d], single-buffered
  __shared__ unsigned short Vs[2][64 * 72];  // V tiles [d][key], double-buffered

  const int qt = blockIdx.x, h = blockIdx.y, bb = blockIdx.z;
  const size_t headoff = (((size_t)bb * N_H + h) * T_DIM) * H_D;
  const unsigned short* Qg = QKV + headoff;
  const unsigned short* Kg = QKV + (size_t)M_TOT * E_DIM + headoff;
  const unsigned short* VTg = VT + (((size_t)bb * N_H + h) * H_D) * T_DIM;

  const int tid = threadIdx.x, lane = tid & 63, wv = tid >> 6;
  const int m15 = lane & 15, quad = lane >> 4;
  const int q0 = qt * 64;
  const int rs = tid >> 3, cs = (tid & 7) * 8;

  // Q staging
  for (int p = 0; p < 2; p++)
    *reinterpret_cast<short8*>(&Qs[(p * 32 + rs) * 72 + cs]) =
        *reinterpret_cast<const short8*>(&Qg[(size_t)(q0 + p * 32 + rs) * H_D + cs]);

  // prefetch tile 0
  short8 kreg[2], vreg[2];
  for (int p = 0; p < 2; p++) {
    kreg[p] = *reinterpret_cast<const short8*>(&Kg[(size_t)(p * 32 + rs) * H_D + cs]);
    vreg[p] = *reinterpret_cast<const short8*>(&VTg[(size_t)(p * 32 + rs) * T_DIM + cs]);
  }
  lds_barrier();

  // hoist Q fragments (wave-private rows; Qs rows become this wave's P strip A)
  bf16x8 aq[2];
  aq[0] = *reinterpret_cast<const bf16x8*>(&Qs[(wv * 16 + m15) * 72 + 0 + quad * 8]);
  aq[1] = *reinterpret_cast<const bf16x8*>(&Qs[(wv * 16 + m15) * 72 + 32 + quad * 8]);

  // stage tile0 (Ks<-K0, Vs[0]<-V0), prefetch tile1
  for (int p = 0; p < 2; p++) {
    *reinterpret_cast<short8*>(&Ks[(p * 32 + rs) * 72 + cs]) = kreg[p];
    *reinterpret_cast<short8*>(&Vs[0][(p * 32 + rs) * 72 + cs]) = vreg[p];
  }
  for (int p = 0; p < 2; p++) {
    kreg[p] = *reinterpret_cast<const short8*>(&Kg[(size_t)(64 + p * 32 + rs) * H_D + cs]);
    vreg[p] = *reinterpret_cast<const short8*>(&VTg[(size_t)(p * 32 + rs) * T_DIM + 64 + cs]);
  }
  lds_barrier();  // tile0 visible

  floatx4 o[4] = {};
  floatx4 lacc = {};
  const short8 ones_s = {0x3f80, 0x3f80, 0x3f80, 0x3f80, 0x3f80, 0x3f80, 0x3f80, 0x3f80};
  const bf16x8 onesb = __builtin_bit_cast(bf16x8, ones_s);
  unsigned short* stripA = &Qs[wv * 16 * 72];
  unsigned short* stripB = &Sb[wv * 16 * 72];

  // ---- prologue iteration 0: QK(0) -> P(0) in strip A ----
  {
    floatx4 s[4] = {};
    for (int kk = 0; kk < 2; kk++)
      for (int j = 0; j < 4; j++) {
        bf16x8 b = *reinterpret_cast<const bf16x8*>(&Ks[(j * 16 + m15) * 72 + kk * 32 + quad * 8]);
        s[j] = __builtin_amdgcn_mfma_f32_16x16x32_bf16(aq[kk], b, s[j], 0, 0, 0);
      }
    lds_barrier();  // all waves done reading Ks (K0)
    // stage tile1 (Ks<-K1, Vs[1]<-V1), prefetch tile2
    for (int p = 0; p < 2; p++) {
      *reinterpret_cast<short8*>(&Ks[(p * 32 + rs) * 72 + cs]) = kreg[p];
      *reinterpret_cast<short8*>(&Vs[1][(p * 32 + rs) * 72 + cs]) = vreg[p];
    }
    for (int p = 0; p < 2; p++) {
      kreg[p] = *reinterpret_cast<const short8*>(&Kg[(size_t)(128 + p * 32 + rs) * H_D + cs]);
      vreg[p] = *reinterpret_cast<const short8*>(&VTg[(size_t)(p * 32 + rs) * T_DIM + 128 + cs]);
    }
    for (int j = 0; j < 4; j++)
      for (int r = 0; r < 4; r++)
        stripA[(quad * 4 + r) * 72 + j * 16 + m15] = f32_to_bf16_trunc(EXP2F(s[j][r]));
  }

  // ---- main loop: iter kt does PV(kt-1) + QK(kt) ----
  for (int kt = 1; kt < 32; kt++) {
    unsigned short* sp_prev = (kt & 1) ? stripA : stripB;
    unsigned short* sp_cur = (kt & 1) ? stripB : stripA;
    const unsigned short* vprev = Vs[(kt - 1) & 1];
    lds_barrier();  // staging from iter kt-1 visible; own strip stores flushed

    // PV(kt-1): independent of this iter's QK chain -> fills MFMA pipe immediately
    for (int kk = 0; kk < 2; kk++) {
      bf16x8 a = *reinterpret_cast<const bf16x8*>(&sp_prev[m15 * 72 + kk * 32 + quad * 8]);
      lacc = __builtin_amdgcn_mfma_f32_16x16x32_bf16(a, onesb, lacc, 0, 0, 0);
      for (int j = 0; j < 4; j++) {
        bf16x8 b = *reinterpret_cast<const bf16x8*>(&vprev[(j * 16 + m15) * 72 + kk * 32 + quad * 8]);
        o[j] = __builtin_amdgcn_mfma_f32_16x16x32_bf16(a, b, o[j], 0, 0, 0);
      }
    }

    // QK(kt)
    floatx4 s[4] = {};
    for (int kk = 0; kk < 2; kk++)
      for (int j = 0; j < 4; j++) {
        bf16x8 b = *reinterpret_cast<const bf16x8*>(&Ks[(j * 16 + m15) * 72 + kk * 32 + quad * 8]);
        s[j] = __builtin_amdgcn_mfma_f32_16x16x32_bf16(aq[kk], b, s[j], 0, 0, 0);
      }
    lds_barrier();  // all waves done reading Ks(kt) and Vs[(kt-1)&1]

    if (kt < 31) {  // stage tile kt+1 (overwrites K(kt), V(kt-1)); prefetch kt+2
      for (int p = 0; p < 2; p++) {
        *reinterpret_cast<short8*>(&Ks[(p * 32 + rs) * 72 + cs]) = kreg[p];
        *reinterpret_cast<short8*>(&Vs[(kt + 1) & 1][(p * 32 + rs) * 72 + cs]) = vreg[p];
      }
      if (kt < 30)
        for (int p = 0; p < 2; p++) {
          kreg[p] = *reinterpret_cast<const short8*>(&Kg[(size_t)((kt + 2) * 64 + p * 32 + rs) * H_D + cs]);
          vreg[p] = *reinterpret_cast<const short8*>(&VTg[(size_t)(p * 32 + rs) * T_DIM + (kt + 2) * 64 + cs]);
        }
    }

    // P(kt) = exp2(S) truncated, into this wave's other strip
    for (int j = 0; j < 4; j++)
      for (int r = 0; r < 4; r++)
        sp_cur[(quad * 4 + r) * 72 + j * 16 + m15] = f32_to_bf16_trunc(EXP2F(s[j][r]));
  }

  // ---- epilogue: PV(31) (strip B, Vs[1]) ----
  asm volatile("s_waitcnt lgkmcnt(0)" ::: "memory");
  for (int kk = 0; kk < 2; kk++) {
    bf16x8 a = *reinterpret_cast<const bf16x8*>(&stripB[m15 * 72 + kk * 32 + quad * 8]);
    lacc = __builtin_amdgcn_mfma_f32_16x16x32_bf16(a, onesb, lacc, 0, 0, 0);
    for (int j = 0; j < 4; j++) {
      bf16x8 b = *reinterpret_cast<const bf16x8*>(&Vs[1][(j * 16 + m15) * 72 + kk * 32 + quad * 8]);
      o[j] = __builtin_amdgcn_mfma_f32_16x16x32_bf16(a, b, o[j], 0, 0, 0);
    }
  }

  for (int r = 0; r < 4; r++) {
    float rl = RCPF(lacc[r]);
    int q = q0 + wv * 16 + quad * 4 + r;
    for (int j = 0; j < 4; j++)
      ctx[(size_t)(bb * T_DIM + q) * E_DIM + h * 64 + j * 16 + m15] = f32_to_bf16(o[j][r] * rl);
  }
}

// ---- output projection: out = ctx @ Wo + bo (fp32) ----
__global__ __launch_bounds__(256) void gemm_out(const unsigned short* __restrict__ Actx,
                                                const unsigned short* __restrict__ Wt,
                                                const float* __restrict__ bias,
                                                float* __restrict__ out) {
  __shared__ unsigned short As[64 * 32];
  __shared__ unsigned short Bs[128 * 32];

  const int tid = threadIdx.x;
  const int lane = tid & 63, wv = tid >> 6;
  const int m15 = lane & 15, quad = lane >> 4;
  const int wm = (wv & 1) * 32, wn = (wv >> 1) * 64;
  const int m0 = blockIdx.x * 64, n0 = blockIdx.y * 128;

  floatx4 acc[2][4] = {};
  const int srow = lane >> 2, scol = (lane & 3) * 8;

  for (int k0 = 0; k0 < E_DIM; k0 += 32) {
    gload_lds16(&Actx[(size_t)(m0 + wv * 16 + srow) * E_DIM + k0 + scol], &As[wv * 512]);
    for (int cc = 0; cc < 2; cc++) {
      int c = wv * 2 + cc;
      gload_lds16(&Wt[(size_t)(n0 + c * 16 + srow) * E_DIM + k0 + scol], &Bs[c * 512]);
    }
    __syncthreads();
    bf16x8 af[2], bfr[4];
    for (int i = 0; i < 2; i++)
      af[i] = *reinterpret_cast<const bf16x8*>(&As[(wm + i * 16 + m15) * 32 + quad * 8]);
    for (int j = 0; j < 4; j++)
      bfr[j] = *reinterpret_cast<const bf16x8*>(&Bs[(wn + j * 16 + m15) * 32 + quad * 8]);
    for (int i = 0; i < 2; i++)
      for (int j = 0; j < 4; j++)
        acc[i][j] = __builtin_amdgcn_mfma_f32_16x16x32_bf16(af[i], bfr[j], acc[i][j], 0, 0, 0);
    __syncthreads();
  }

  for (int i = 0; i < 2; i++)
    for (int j = 0; j < 4; j++) {
      int gn = n0 + wn + j * 16 + m15;
      float bso = bias[gn];
      for (int r = 0; r < 4; r++) {
        int gm = m0 + wm + i * 16 + quad * 4 + r;
        out[(size_t)gm * E_DIM + gn] = acc[i][j][r] + bso;
      }
    }
}

extern "C" void kernel_launch(void* const* d_in, const int* in_sizes, int n_in,
                              void* d_out, int out_size, void* d_ws, size_t ws_size,
                              hipStream_t stream) {
  const float* query  = (const float*)d_in[0];
  const float* key_in = (const float*)d_in[1];
  const float* value  = (const float*)d_in[2];
  const float* Wq = (const float*)d_in[3];
  const float* bq = (const float*)d_in[4];
  const float* Wk = (const float*)d_in[5];
  const float* bk = (const float*)d_in[6];
  const float* Wv = (const float*)d_in[7];
  const float* bv = (const float*)d_in[8];
  const float* Wo = (const float*)d_in[9];
  const float* bo = (const float*)d_in[10];
  float* out = (float*)d_out;

  // ws layout (bf16): Wt[4][768][768] | Xb[3][4096][768] | QKV[3][4096][768] | VT[2][12][64][2048] | ctx[4096][768]
  unsigned short* ws  = (unsigned short*)d_ws;
  unsigned short* Wt  = ws;
  unsigned short* Xb  = Wt + (size_t)4 * E_DIM * E_DIM;
  unsigned short* QKV = Xb + (size_t)3 * M_TOT * E_DIM;
  unsigned short* VT  = QKV + (size_t)3 * M_TOT * E_DIM;
  unsigned short* ctx = VT + (size_t)N_B * N_H * H_D * T_DIM;

  dim3 tb(256);
  convert_x<<<dim3(M_TOT * E_DIM / 1024, 3), tb, 0, stream>>>(query, key_in, value, Xb);
  transpose_w4<<<dim3(24, 24, 4), tb, 0, stream>>>(Wq, Wk, Wv, Wo, Wt);

  gemm_qkv<<<dim3(32, 6, 3), tb, 0, stream>>>(Xb, Wt, bq, bk, bv, QKV);
  transpose_v<<<dim3(32, 12, 2), tb, 0, stream>>>(QKV + (size_t)2 * M_TOT * E_DIM, VT);
  attn<<<dim3(32, 12, 2), tb, 0, stream>>>(QKV, VT, ctx);
  gemm_out<<<dim3(64, 6), tb, 0, stream>>>(ctx, Wt + (size_t)3 * E_DIM * E_DIM, bo, out);
  (void)in_sizes; (void)n_in; (void)out_size; (void)ws_size;
}